// Round 1
// baseline (5289.116 us; speedup 1.0000x reference)
//
#include <hip/hip_runtime.h>
#include <hip/hip_bf16.h>

#define B_ 16
#define T_ 32
#define S_ 256
#define K_ 8
#define L_ 64
#define V_ 32000
#define VX_ 32050
#define NEG_ -1e10f

__device__ __forceinline__ float fsigmoid(float x){ return 1.f/(1.f+__expf(-x)); }
__device__ __forceinline__ float ftanh(float x){ float e=__expf(2.f*x); return 1.f - 2.f/(e+1.f); }

// ---------------- embed fill: X[t][b][0:512] = embedding[tgt[b][t]] ----------------
__global__ void k_embed(const float* __restrict__ emb, const int* __restrict__ tgt, float* __restrict__ X){
  int idx = blockIdx.x*256 + threadIdx.x;
  if (idx >= T_*B_*512) return;
  int t = idx >> 13; int b = (idx >> 9) & 15; int e = idx & 511;
  int tok = tgt[b*T_ + t];
  X[(size_t)(t*B_+b)*1536 + e] = emb[(size_t)tok*512 + e];
}

// ---------------- generic f32 GEMM: C[M,N] = A[M,K] * W[N,K]^T + bias ----------------
// tiles 128x64, K_T=16. grid = (M/128, N/64). PERM: A-row r=t*16+b -> C-row b*32+t.
template<bool PERM>
__global__ __launch_bounds__(256) void k_gemm(const float* __restrict__ A, const float* __restrict__ W,
    const float* __restrict__ bias, float* __restrict__ C, int K, int ldC){
  __shared__ float As[16][132];
  __shared__ float Ws[16][68];
  const int m0 = blockIdx.x*128, n0 = blockIdx.y*64;
  const int tid = threadIdx.x;
  const int tm = tid & 15, tn = tid >> 4;
  float acc[8][4];
#pragma unroll
  for (int i=0;i<8;++i)
#pragma unroll
    for(int j=0;j<4;++j) acc[i][j]=0.f;
  for (int k0=0;k0<K;k0+=16){
#pragma unroll
    for (int rr=0;rr<2;++rr){
      int f = tid + rr*256;
      int mm = f >> 2, kc = f & 3;
      const float4 v = *(const float4*)(A + (size_t)(m0+mm)*K + k0 + kc*4);
      As[kc*4+0][mm]=v.x; As[kc*4+1][mm]=v.y; As[kc*4+2][mm]=v.z; As[kc*4+3][mm]=v.w;
    }
    {
      int nn = tid >> 2, kc = tid & 3;
      const float4 v = *(const float4*)(W + (size_t)(n0+nn)*K + k0 + kc*4);
      Ws[kc*4+0][nn]=v.x; Ws[kc*4+1][nn]=v.y; Ws[kc*4+2][nn]=v.z; Ws[kc*4+3][nn]=v.w;
    }
    __syncthreads();
#pragma unroll
    for (int kk=0;kk<16;++kk){
      float a[8], w[4];
      float4 a0 = *(const float4*)&As[kk][tm*8];
      float4 a1 = *(const float4*)&As[kk][tm*8+4];
      float4 w0 = *(const float4*)&Ws[kk][tn*4];
      a[0]=a0.x;a[1]=a0.y;a[2]=a0.z;a[3]=a0.w;a[4]=a1.x;a[5]=a1.y;a[6]=a1.z;a[7]=a1.w;
      w[0]=w0.x;w[1]=w0.y;w[2]=w0.z;w[3]=w0.w;
#pragma unroll
      for (int i=0;i<8;++i)
#pragma unroll
        for (int j=0;j<4;++j) acc[i][j] += a[i]*w[j];
    }
    __syncthreads();
  }
#pragma unroll
  for (int i=0;i<8;++i){
    int m = m0 + tm*8 + i;
    size_t row = PERM ? (size_t)((m&15)*T_ + (m>>4)) : (size_t)m;
#pragma unroll
    for (int j=0;j<4;++j){
      int n = n0 + tn*4 + j;
      C[row*(size_t)ldC + n] = acc[i][j] + (bias ? bias[n] : 0.f);
    }
  }
}

// ---------------- per-step attention (one block per b, 1024 threads) ----------------
__global__ __launch_bounds__(1024) void k_attn(const float* __restrict__ h,
    const float* __restrict__ PVS, const float* __restrict__ PVK,
    const float* __restrict__ src, const float* __restrict__ kgh,
    const float* __restrict__ Wq_c, const float* __restrict__ Wq_k,
    const float* __restrict__ Vw_c, const float* __restrict__ bV_c,
    const float* __restrict__ Vw_k, const float* __restrict__ bV_k,
    const float* __restrict__ smask, const float* __restrict__ kmask,
    float* __restrict__ Xt, float* __restrict__ KWt){
  const int b = blockIdx.x, tid = threadIdx.x;
  __shared__ float hs[512], hqc[512], hqk[512];
  __shared__ float part[1024];
  __shared__ float e[256];
  __shared__ float ek[8], kw[8];
  __shared__ float sc0;
  if (tid < 512) hs[tid] = h[b*512 + tid];
  __syncthreads();
  { // hq_c (tid<512) / hq_k (tid>=512): 512-length dots
    int j = tid & 511;
    const float* Wrow = (tid < 512 ? Wq_c : Wq_k) + (size_t)j*512;
    const float4* w4 = (const float4*)Wrow;
    const float4* h4 = (const float4*)hs;
    float s = 0.f;
#pragma unroll 4
    for (int i=0;i<128;++i){ float4 w=w4[i], hv=h4[i]; s += w.x*hv.x + w.y*hv.y + w.z*hv.z + w.w*hv.w; }
    if (tid < 512) hqc[j] = s; else hqk[j] = s;
  }
  __syncthreads();
  { // e_src partials: 256 s * 4 h-quarters
    int s_i = tid >> 2, q = tid & 3;
    const float4* pv4 = (const float4*)(PVS + ((size_t)(b*S_ + s_i))*512 + q*128);
    const float4* hq4 = (const float4*)(hqc + q*128);
    const float4* vw4 = (const float4*)(Vw_c + q*128);
    float p = 0.f;
#pragma unroll 4
    for (int m=0;m<32;++m){
      float4 pv=pv4[m], hq=hq4[m], vw=vw4[m];
      p += ftanh(pv.x+hq.x)*vw.x + ftanh(pv.y+hq.y)*vw.y + ftanh(pv.z+hq.z)*vw.z + ftanh(pv.w+hq.w)*vw.w;
    }
    part[tid] = p;
  }
  __syncthreads();
  if (tid < 256){
    float v = part[tid*4]+part[tid*4+1]+part[tid*4+2]+part[tid*4+3] + bV_c[0];
    if (smask[b*S_ + tid] == 0.f) v += NEG_;
    e[tid] = v;
  }
  if (tid < 512){ // e_kg: 8 keys, one wave each
    int k = tid >> 6, l = tid & 63;
    const float* pvk = PVK + (size_t)(b*K_ + k)*512;
    float p = 0.f;
#pragma unroll
    for (int m=0;m<8;++m){ int hh = l + m*64; p += ftanh(pvk[hh] + hqk[hh]) * Vw_k[hh]; }
#pragma unroll
    for (int off=32; off>0; off>>=1) p += __shfl_down(p, off, 64);
    if (l == 0){
      float v = p + bV_k[0];
      if (kmask[b*K_ + k] == 0.f) v += NEG_;
      ek[k] = v;
    }
  }
  __syncthreads();
  // softmax over e[256]
  if (tid < 256) part[tid] = e[tid];
  __syncthreads();
  for (int s=128;s>0;s>>=1){ if (tid<s) part[tid]=fmaxf(part[tid],part[tid+s]); __syncthreads(); }
  float M = part[0];
  __syncthreads();
  if (tid < 256){ float ex = __expf(e[tid]-M); e[tid] = ex; part[tid] = ex; }
  __syncthreads();
  for (int s=128;s>0;s>>=1){ if (tid<s) part[tid]+=part[tid+s]; __syncthreads(); }
  if (tid == 0) sc0 = 1.f/part[0];
  if (tid == 1){ // kg softmax (8 elems)
    float mk = ek[0];
#pragma unroll
    for (int k=1;k<8;++k) mk = fmaxf(mk, ek[k]);
    float z = 0.f; float tmp[8];
#pragma unroll
    for (int k=0;k<8;++k){ tmp[k]=__expf(ek[k]-mk); z+=tmp[k]; }
    float iz = 1.f/z;
#pragma unroll
    for (int k=0;k<8;++k){ kw[k]=tmp[k]*iz; KWt[b*8+k]=kw[k]; }
  }
  __syncthreads();
  if (tid < 512){ // c_t
    int j = tid;
    const float* sp = src + (size_t)b*S_*512 + j;
    float accv = 0.f;
#pragma unroll 4
    for (int s2=0;s2<256;++s2) accv += e[s2] * sp[(size_t)s2*512];
    Xt[(size_t)b*1536 + 512 + j] = accv * sc0;
  } else { // k_t
    int j = tid - 512;
    const float* kp = kgh + (size_t)b*K_*512 + j;
    float accv = 0.f;
#pragma unroll
    for (int k=0;k<8;++k) accv += kw[k] * kp[(size_t)k*512];
    Xt[(size_t)b*1536 + 1024 + j] = accv;
  }
}

// ---------------- GRU matmul partials: gi (blocks 0..95, split-K 4), gh (96..143, split-K 2) ----------------
__global__ __launch_bounds__(256) void k_grumm(const float* __restrict__ Xt, const float* __restrict__ h,
    const float* __restrict__ W_ih, const float* __restrict__ W_hh,
    float* __restrict__ GIP, float* __restrict__ GHP){
  __shared__ float As[16][33];
  __shared__ float Ws[64][33];
  const int bid = blockIdx.x, tid = threadIdx.x;
  const float* A; const float* Wp; float* out; int ldA, k0, ksteps, n0;
  if (bid < 96){
    int nt = bid % 24, ks = bid / 24;
    A = Xt; ldA = 1536; Wp = W_ih; n0 = nt*64; k0 = ks*384; ksteps = 12;
    out = GIP + (size_t)ks*16*1536;
  } else {
    int b2 = bid - 96; int nt = b2 % 24, ks = b2 / 24;
    A = h; ldA = 512; Wp = W_hh; n0 = nt*64; k0 = ks*256; ksteps = 8;
    out = GHP + (size_t)ks*16*1536;
  }
  const int tb = tid & 15, jg = tid >> 4;
  float acc[4] = {0.f,0.f,0.f,0.f};
  for (int s=0;s<ksteps;++s){
    int kb = k0 + s*32;
    if (tid < 128){
      int bb = tid >> 3, kc = tid & 7;
      float4 v = *(const float4*)(A + (size_t)bb*ldA + kb + kc*4);
      As[bb][kc*4+0]=v.x; As[bb][kc*4+1]=v.y; As[bb][kc*4+2]=v.z; As[bb][kc*4+3]=v.w;
    }
#pragma unroll
    for (int r=0;r<2;++r){
      int f = tid + r*256;
      int row = f >> 3, kc = f & 7;
      float4 v = *(const float4*)(Wp + (size_t)(n0+row)*ldA + kb + kc*4);
      Ws[row][kc*4+0]=v.x; Ws[row][kc*4+1]=v.y; Ws[row][kc*4+2]=v.z; Ws[row][kc*4+3]=v.w;
    }
    __syncthreads();
#pragma unroll 8
    for (int kk=0;kk<32;++kk){
      float av = As[tb][kk];
      acc[0] += av * Ws[jg*4+0][kk];
      acc[1] += av * Ws[jg*4+1][kk];
      acc[2] += av * Ws[jg*4+2][kk];
      acc[3] += av * Ws[jg*4+3][kk];
    }
    __syncthreads();
  }
#pragma unroll
  for (int jj=0;jj<4;++jj) out[(size_t)tb*1536 + n0 + jg*4 + jj] = acc[jj];
}

// ---------------- GRU gates ----------------
__global__ void k_gates(const float* __restrict__ GIP, const float* __restrict__ GHP,
    const float* __restrict__ b_ih, const float* __restrict__ b_hh,
    const float* __restrict__ h, float* __restrict__ sout){
  int idx = blockIdx.x*256 + threadIdx.x;
  if (idx >= 16*512) return;
  int b = idx >> 9, j = idx & 511;
  float gi[3], gh[3];
#pragma unroll
  for (int g=0; g<3; ++g){
    int row = g*512 + j;
    float v = b_ih[row];
#pragma unroll
    for (int ks=0; ks<4; ++ks) v += GIP[(size_t)ks*24576 + b*1536 + row];
    gi[g] = v;
    gh[g] = b_hh[row] + GHP[b*1536 + row] + GHP[24576 + b*1536 + row];
  }
  float r = fsigmoid(gi[0] + gh[0]);
  float z = fsigmoid(gi[1] + gh[1]);
  float n = ftanh(gi[2] + r*gh[2]);
  float hv = h[b*512 + j];
  sout[b*512 + j] = (1.f - z)*n + z*hv;
}

// ---------------- build CAT4 = [s, c, k, kf] (512 x 2048) ----------------
__global__ void k_cat4(const float* __restrict__ S_all, const float* __restrict__ X,
    const float* __restrict__ kgf, float* __restrict__ CAT){
  int idx = blockIdx.x*256 + threadIdx.x;
  if (idx >= 512*2048) return;
  int r = idx >> 11, c = idx & 2047;
  float v;
  if (c < 512) v = S_all[(size_t)r*512 + c];
  else if (c < 1536) v = X[(size_t)r*1536 + c];   // c_t at [512,1024), k_t at [1024,1536)
  else v = kgf[(r & 15)*512 + (c - 1536)];
  CAT[idx] = v;
}

// ---------------- ptr = sigmoid([c,s,y,kf,k] . Wptr + bptr), one wave per row ----------------
__global__ __launch_bounds__(256) void k_ptr(const float* __restrict__ X, const float* __restrict__ S_all,
    const float* __restrict__ kgf, const float* __restrict__ Wptr, const float* __restrict__ bptr,
    float* __restrict__ PTR){
  int r = blockIdx.x*4 + (threadIdx.x >> 6);
  int lane = threadIdx.x & 63;
  const float* seg[5];
  seg[0] = X + (size_t)r*1536 + 512;
  seg[1] = S_all + (size_t)r*512;
  seg[2] = X + (size_t)r*1536;
  seg[3] = kgf + (r & 15)*512;
  seg[4] = X + (size_t)r*1536 + 1024;
  float s = 0.f;
#pragma unroll
  for (int g=0; g<5; ++g){
    const float* p = seg[g];
    const float* w = Wptr + g*512;
#pragma unroll
    for (int m=0;m<8;++m){ int i = lane + m*64; s += p[i]*w[i]; }
  }
#pragma unroll
  for (int off=32;off>0;off>>=1) s += __shfl_down(s, off, 64);
  if (lane == 0) PTR[r] = fsigmoid(s + bptr[0]);
}

// ---------------- softmax over V, * ptr, zero extras; one block per out-row ----------------
__global__ __launch_bounds__(256) void k_softmax(float* __restrict__ out, const float* __restrict__ PTR){
  int orow = blockIdx.x;
  int b = orow >> 5, t = orow & 31;
  int r = t*16 + b;
  float* f = out + (size_t)orow * VX_;
  __shared__ float red[256];
  int tid = threadIdx.x;
  float lm = -1e30f;
  for (int v = tid; v < V_; v += 256) lm = fmaxf(lm, f[v]);
  red[tid] = lm; __syncthreads();
  for (int s=128;s>0;s>>=1){ if (tid<s) red[tid]=fmaxf(red[tid],red[tid+s]); __syncthreads(); }
  float M = red[0]; __syncthreads();
  float ls = 0.f;
  for (int v = tid; v < V_; v += 256){ float e2 = __expf(f[v]-M); f[v] = e2; ls += e2; }
  red[tid] = ls; __syncthreads();
  for (int s=128;s>0;s>>=1){ if (tid<s) red[tid]+=red[tid+s]; __syncthreads(); }
  float scale = PTR[r] / red[0];
  for (int v = tid; v < V_; v += 256) f[v] *= scale;
  for (int v = V_ + tid; v < VX_; v += 256) f[v] = 0.f;
}

// ---------------- copy-dist + scatter: grid (b,k,tgroup) = 16*8*4 ----------------
__global__ __launch_bounds__(256) void k_scatter(const float* __restrict__ Q, const float* __restrict__ kgo,
    const float* __restrict__ kpmask, const int* __restrict__ kev, const float* __restrict__ KW,
    const float* __restrict__ PTR, float* __restrict__ out){
  int bid = blockIdx.x;
  int tg = bid & 3, k = (bid >> 2) & 7, b = bid >> 5;
  int tid = threadIdx.x;
  int l = tid >> 2, qtr = tid & 3;
  __shared__ float qs[512];
  __shared__ float part[256];
  const float* kgrow = kgo + (size_t)((b*8 + k)*64 + l) * 512;
  for (int tt=0; tt<8; ++tt){
    int t = tg*8 + tt;
    int r = t*16 + b;
    int orow = b*32 + t;
    qs[tid] = Q[(size_t)r*512 + tid];
    qs[256 + tid] = Q[(size_t)r*512 + 256 + tid];
    __syncthreads();
    float p = 0.f;
    const float4* q4 = (const float4*)(qs) + qtr*32;
    const float4* k4 = (const float4*)(kgrow) + qtr*32;
#pragma unroll 4
    for (int m=0;m<32;++m){ float4 a=q4[m], c=k4[m]; p += a.x*c.x+a.y*c.y+a.z*c.z+a.w*c.w; }
    part[tid] = p;
    __syncthreads();
    if (tid < 64){
      float ev = part[tid*4]+part[tid*4+1]+part[tid*4+2]+part[tid*4+3];
      if (kpmask[(b*8+k)*64 + tid] == 0.f) ev += NEG_;
      float mx = ev;
#pragma unroll
      for (int off=32;off>0;off>>=1) mx = fmaxf(mx, __shfl_xor(mx, off, 64));
      float ex = __expf(ev - mx);
      float z = ex;
#pragma unroll
      for (int off=32;off>0;off>>=1) z += __shfl_xor(z, off, 64);
      float val = (ex/z) * KW[t*128 + b*8 + k] * (1.f - PTR[r]);
      atomicAdd(out + (size_t)orow*VX_ + kev[(b*8+k)*64 + tid], val);
    }
    __syncthreads();
  }
}

// ---------------- final normalize ----------------
__global__ __launch_bounds__(256) void k_norm(float* __restrict__ out){
  int orow = blockIdx.x;
  float* f = out + (size_t)orow*VX_;
  __shared__ float red[256];
  int tid = threadIdx.x;
  float ls = 0.f;
  for (int v=tid; v<VX_; v+=256) ls += f[v];
  red[tid]=ls; __syncthreads();
  for (int s=128;s>0;s>>=1){ if (tid<s) red[tid]+=red[tid+s]; __syncthreads(); }
  float inv = 1.f/red[0];
  for (int v=tid; v<VX_; v+=256) f[v] *= inv;
}

extern "C" void kernel_launch(void* const* d_in, const int* in_sizes, int n_in,
                              void* d_out, int out_size, void* d_ws, size_t ws_size,
                              hipStream_t stream) {
  const int*   tgt   = (const int*)  d_in[0];
  const float* inith = (const float*)d_in[1];
  const float* src   = (const float*)d_in[2];
  const float* smask = (const float*)d_in[3];
  const float* kgh   = (const float*)d_in[4];
  const float* kgf   = (const float*)d_in[5];
  const float* kgo   = (const float*)d_in[6];
  const float* kmask = (const float*)d_in[7];
  const float* kpmask= (const float*)d_in[8];
  const int*   kev   = (const int*)  d_in[10];
  const float* emb   = (const float*)d_in[12];
  const float* W_ih  = (const float*)d_in[13];
  const float* W_hh  = (const float*)d_in[14];
  const float* b_ih  = (const float*)d_in[15];
  const float* b_hh  = (const float*)d_in[16];
  const float* Wq_c  = (const float*)d_in[17];
  const float* Wv_c  = (const float*)d_in[18];
  const float* bv_c  = (const float*)d_in[19];
  const float* Vw_c  = (const float*)d_in[20];
  const float* bV_c  = (const float*)d_in[21];
  const float* Wq_k  = (const float*)d_in[22];
  const float* Wv_k  = (const float*)d_in[23];
  const float* bv_k  = (const float*)d_in[24];
  const float* Vw_k  = (const float*)d_in[25];
  const float* bV_k  = (const float*)d_in[26];
  const float* W1    = (const float*)d_in[27];
  const float* b1    = (const float*)d_in[28];
  const float* W2    = (const float*)d_in[29];
  const float* b2    = (const float*)d_in[30];
  const float* Wptr  = (const float*)d_in[31];
  const float* bptr  = (const float*)d_in[32];
  const float* Wcpy  = (const float*)d_in[33];
  const float* bcpy  = (const float*)d_in[34];
  float* out = (float*)d_out;

  float* Xb    = (float*)d_ws;            // (T,B,1536)
  float* S_all = Xb    + 786432;          // (T,B,512)
  float* PVS   = S_all + 262144;          // (B,S,512)
  float* PVK   = PVS   + 2097152;         // (B,8,512)
  float* KW    = PVK   + 65536;           // (T,B,8)
  float* GIP   = KW    + 4096;            // (4,16,1536)
  float* GHP   = GIP   + 98304;           // (2,16,1536)
  float* CAT   = GHP   + 49152;           // (512,2048)
  float* HID   = CAT   + 1048576;         // (512,512)
  float* Qb    = HID   + 262144;          // (512,512)
  float* PTR   = Qb    + 262144;          // (512)

  // prep
  k_embed<<<(T_*B_*512+255)/256, 256, 0, stream>>>(emb, tgt, Xb);
  k_gemm<false><<<dim3(32,8), 256, 0, stream>>>(src, Wv_c, bv_c, PVS, 512, 512);
  k_gemm<false><<<dim3(1,8),  256, 0, stream>>>(kgh, Wv_k, bv_k, PVK, 512, 512);

  // sequential recurrence
  for (int t = 0; t < T_; ++t){
    const float* h = (t == 0) ? inith : (S_all + (size_t)(t-1)*B_*512);
    float* Xt = Xb + (size_t)t*B_*1536;
    k_attn<<<16, 1024, 0, stream>>>(h, PVS, PVK, src, kgh, Wq_c, Wq_k, Vw_c, bV_c, Vw_k, bV_k,
                                    smask, kmask, Xt, KW + t*B_*K_);
    k_grumm<<<144, 256, 0, stream>>>(Xt, h, W_ih, W_hh, GIP, GHP);
    k_gates<<<32, 256, 0, stream>>>(GIP, GHP, b_ih, b_hh, h, S_all + (size_t)t*B_*512);
  }

  // parallel epilogue
  k_cat4<<<(512*2048+255)/256, 256, 0, stream>>>(S_all, Xb, kgf, CAT);
  k_gemm<false><<<dim3(4,8),   256, 0, stream>>>(CAT, W1, b1, HID, 2048, 512);
  k_gemm<false><<<dim3(4,8),   256, 0, stream>>>(S_all, Wcpy, bcpy, Qb, 512, 512);
  k_ptr<<<128, 256, 0, stream>>>(Xb, S_all, kgf, Wptr, bptr, PTR);
  k_gemm<true><<<dim3(4,500),  256, 0, stream>>>(HID, W2, b2, out, 512, VX_);
  k_softmax<<<512, 256, 0, stream>>>(out, PTR);
  k_scatter<<<512, 256, 0, stream>>>(Qb, kgo, kpmask, kev, KW, PTR, out);
  k_norm<<<512, 256, 0, stream>>>(out);
}